// Round 8
// baseline (475.597 us; speedup 1.0000x reference)
//
#include <hip/hip_runtime.h>
#include <math.h>

static inline size_t align256(size_t x) { return (x + 255) & ~size_t(255); }

// ============ CSR construction via radix-8 dst-octant binning ============

// exact bucket totals (8 global atomics per block)
__global__ __launch_bounds__(256) void bucket_hist(const int* __restrict__ dst,
                                                   int* __restrict__ btot, int E, int BN) {
    __shared__ int hsh[8];
    if (threadIdx.x < 8) hsh[threadIdx.x] = 0;
    __syncthreads();
    for (int e = blockIdx.x * 256 + threadIdx.x; e < E; e += gridDim.x * 256) {
        int b = (int)(((long long)dst[e] * 8) / BN);
        atomicAdd(&hsh[b], 1);
    }
    __syncthreads();
    if (threadIdx.x < 8 && hsh[threadIdx.x]) atomicAdd(&btot[threadIdx.x], hsh[threadIdx.x]);
}

// bin (src,dst) pairs into 8 contiguous bucket regions (block-level reservation)
__global__ __launch_bounds__(256) void bin_edges(const int* __restrict__ src,
                                                 const int* __restrict__ dst,
                                                 const int* __restrict__ btot,
                                                 int* __restrict__ bcur,
                                                 int2* __restrict__ bins, int E, int BN) {
    __shared__ int hist[8], gbase[8], lcur[8], bpref[8];
    if (threadIdx.x == 0) {
        int pre = 0;
        for (int b = 0; b < 8; ++b) { bpref[b] = pre; pre += btot[b]; }
    }
    if (threadIdx.x < 8) hist[threadIdx.x] = 0;
    __syncthreads();
    int e0 = blockIdx.x * 1024;
    int m = E - e0; if (m > 1024) m = 1024;
    int b_[4]; int2 p_[4];
#pragma unroll
    for (int k = 0; k < 4; ++k) {
        int j = threadIdx.x + k * 256;
        if (j < m) {
            int s = src[e0 + j], d = dst[e0 + j];
            int b = (int)(((long long)d * 8) / BN);
            b_[k] = b; p_[k] = make_int2(s, d);
            atomicAdd(&hist[b], 1);
        } else b_[k] = -1;
    }
    __syncthreads();
    if (threadIdx.x < 8) {
        int c = hist[threadIdx.x];
        gbase[threadIdx.x] = c ? atomicAdd(&bcur[threadIdx.x], c) : 0;
        lcur[threadIdx.x] = 0;
    }
    __syncthreads();
#pragma unroll
    for (int k = 0; k < 4; ++k) {
        if (b_[k] >= 0) {
            int b = b_[k];
            int pos = atomicAdd(&lcur[b], 1);
            bins[(size_t)bpref[b] + gbase[b] + pos] = p_[k];
        }
    }
}

// sharded degree count over bucket region s (XCD-local atomics)
__global__ __launch_bounds__(256) void count_binned(const int2* __restrict__ bins,
                                                    const int* __restrict__ btot,
                                                    int* __restrict__ counts, int E) {
    int s  = blockIdx.x & 7;
    int bs = blockIdx.x >> 3, nbk = gridDim.x >> 3;
    int lo = 0;
#pragma unroll
    for (int b = 0; b < 8; ++b) lo += (b < s) ? btot[b] : 0;
    int n = btot[s];
    for (int j = bs * 256 + threadIdx.x; j < n; j += nbk * 256)
        atomicAdd(&counts[bins[(size_t)lo + j].y], 1);
}

__global__ __launch_bounds__(256) void block_reduce(const int* __restrict__ counts,
                                                    int* __restrict__ bsum, int BN) {
    __shared__ int red[256];
    int base = blockIdx.x * 1024;
    int s = 0;
    for (int k = threadIdx.x; k < 1024; k += 256) {
        int idx = base + k;
        s += (idx < BN) ? counts[idx] : 0;
    }
    red[threadIdx.x] = s;
    __syncthreads();
    for (int off = 128; off >= 1; off >>= 1) {
        if (threadIdx.x < off) red[threadIdx.x] += red[threadIdx.x + off];
        __syncthreads();
    }
    if (threadIdx.x == 0) bsum[blockIdx.x] = red[0];
}

__global__ __launch_bounds__(1024) void scan_small(const int* __restrict__ bsum,
                                                   int* __restrict__ bpre, int nb) {
    __shared__ int buf[1024];
    int tid = threadIdx.x;
    buf[tid] = (tid < nb) ? bsum[tid] : 0;
    __syncthreads();
    for (int off = 1; off < 1024; off <<= 1) {
        int v = (tid >= off) ? buf[tid - off] : 0;
        __syncthreads();
        buf[tid] += v;
        __syncthreads();
    }
    if (tid < nb) bpre[tid] = (tid == 0) ? 0 : buf[tid - 1];
}

__global__ __launch_bounds__(256) void block_scan(const int* __restrict__ counts,
                                                  const int* __restrict__ bpre,
                                                  int* __restrict__ offs, int BN) {
    __shared__ int tsum[256];
    int base = blockIdx.x * 1024;
    int tbase = base + threadIdx.x * 4;
    int c0 = 0, c1 = 0, c2 = 0, c3 = 0;
    if (tbase + 0 < BN) c0 = counts[tbase + 0];
    if (tbase + 1 < BN) c1 = counts[tbase + 1];
    if (tbase + 2 < BN) c2 = counts[tbase + 2];
    if (tbase + 3 < BN) c3 = counts[tbase + 3];
    int local = c0 + c1 + c2 + c3;
    tsum[threadIdx.x] = local;
    __syncthreads();
    for (int off = 1; off < 256; off <<= 1) {
        int v = (threadIdx.x >= off) ? tsum[threadIdx.x - off] : 0;
        __syncthreads();
        tsum[threadIdx.x] += v;
        __syncthreads();
    }
    int prefix = bpre[blockIdx.x] + tsum[threadIdx.x] - local;  // exclusive
    if (tbase + 0 < BN) offs[tbase + 0] = prefix;
    prefix += c0;
    if (tbase + 1 < BN) offs[tbase + 1] = prefix;
    prefix += c1;
    if (tbase + 2 < BN) offs[tbase + 2] = prefix;
    prefix += c2;
    if (tbase + 3 < BN) offs[tbase + 3] = prefix;
}

// sharded fill over bucket region s (XCD-local cursor atomics + esrc stores)
__global__ __launch_bounds__(256) void fill_binned(const int2* __restrict__ bins,
                                                   const int* __restrict__ btot,
                                                   int* __restrict__ cursor,
                                                   int* __restrict__ esrc, int E) {
    int s  = blockIdx.x & 7;
    int bs = blockIdx.x >> 3, nbk = gridDim.x >> 3;
    int lo = 0;
#pragma unroll
    for (int b = 0; b < 8; ++b) lo += (b < s) ? btot[b] : 0;
    int n = btot[s];
    for (int j = bs * 256 + threadIdx.x; j < n; j += nbk * 256) {
        int2 p = bins[(size_t)lo + j];
        esrc[atomicAdd(&cursor[p.y], 1)] = p.x;
    }
}

// ============ fused layer 1: gather16 + lin1 + relu ============
__global__ __launch_bounds__(256) void gin1_fused(const float* __restrict__ h,
                                                  const int* __restrict__ offs,
                                                  const int* __restrict__ cnts,
                                                  const int* __restrict__ esrc,
                                                  const float* __restrict__ W1,
                                                  const float* __restrict__ b1,
                                                  float* __restrict__ h1, int BN) {
    __shared__ float xb[4][16];
    __shared__ int   ibuf[4][64];
    int tid = threadIdx.x;
    int lane = tid & 63, wv = tid >> 6;
    int fg = lane >> 4, ft = lane & 15;
    int gw = (int)((blockIdx.x * blockDim.x + tid) >> 6);
    int nw = (int)((gridDim.x * blockDim.x) >> 6);
    float wcol[16];
#pragma unroll
    for (int k = 0; k < 16; ++k) wcol[k] = W1[k * 64 + lane];
    float breg = b1[lane];
    for (int i = gw; i < BN; i += nw) {
        float acc = (fg == 0) ? h[(size_t)i * 16 + ft] : 0.f;
        int start = offs[i], deg = cnts[i];
        for (int j0 = 0; j0 < deg; j0 += 64) {
            int m = min(64, deg - j0);
            if (lane < m) ibuf[wv][lane] = esrc[start + j0 + lane];
            int jj = fg;
            for (; jj + 4 < m; jj += 8) {
                int s0 = ibuf[wv][jj];
                int s1 = ibuf[wv][jj + 4];
                acc += h[(size_t)s0 * 16 + ft] + h[(size_t)s1 * 16 + ft];
            }
            if (jj < m) acc += h[(size_t)ibuf[wv][jj] * 16 + ft];
        }
        acc += __shfl_xor(acc, 16, 64);
        acc += __shfl_xor(acc, 32, 64);
        if (lane < 16) xb[wv][lane] = acc;
        float o = breg;
#pragma unroll
        for (int k4 = 0; k4 < 4; ++k4) {
            float4 xv = *(const float4*)&xb[wv][k4 * 4];
            o = fmaf(xv.x, wcol[k4 * 4 + 0], o);
            o = fmaf(xv.y, wcol[k4 * 4 + 1], o);
            o = fmaf(xv.z, wcol[k4 * 4 + 2], o);
            o = fmaf(xv.w, wcol[k4 * 4 + 3], o);
        }
        h1[(size_t)i * 64 + lane] = fmaxf(o, 0.f);
    }
}

// ============ fused layer 2: gather + lin2 + relu + project to (q, r) ============
__global__ __launch_bounds__(256, 4) void gather64_lin2_qr(const float* __restrict__ h1,
                                                           const int* __restrict__ offs,
                                                           const int* __restrict__ cnts,
                                                           const int* __restrict__ esrc,
                                                           const float* __restrict__ W2,
                                                           const float* __restrict__ b2,
                                                           const float* __restrict__ wlin,
                                                           float* __restrict__ q,
                                                           float* __restrict__ r, int BN) {
    __shared__ float xbuf[4][64];
    __shared__ int   ibuf[4][64];
    int tid = threadIdx.x;
    int lane = tid & 63, wv = tid >> 6;
    int gw = (int)((blockIdx.x * blockDim.x + tid) >> 6);
    int nw = (int)((gridDim.x * blockDim.x) >> 6);
    float wcol[64];
#pragma unroll
    for (int k = 0; k < 64; ++k) wcol[k] = W2[k * 64 + lane];
    float breg = b2[lane];
    float wlo = wlin[lane];
    float whi = wlin[64 + lane];
    const float* hl = h1 + lane;
    for (int i = gw; i < BN; i += nw) {
        float acc = hl[(size_t)i * 64];
        int start = offs[i], deg = cnts[i];
        for (int j0 = 0; j0 < deg; j0 += 64) {
            int m = min(64, deg - j0);
            if (lane < m) ibuf[wv][lane] = esrc[start + j0 + lane];
            int jj = 0;
            for (; jj + 8 <= m; jj += 8) {
                int4 ia = *(const int4*)&ibuf[wv][jj];
                int4 ib = *(const int4*)&ibuf[wv][jj + 4];
                float v0 = hl[(size_t)ia.x * 64];
                float v1 = hl[(size_t)ia.y * 64];
                float v2 = hl[(size_t)ia.z * 64];
                float v3 = hl[(size_t)ia.w * 64];
                float v4 = hl[(size_t)ib.x * 64];
                float v5 = hl[(size_t)ib.y * 64];
                float v6 = hl[(size_t)ib.z * 64];
                float v7 = hl[(size_t)ib.w * 64];
                acc += ((v0 + v1) + (v2 + v3)) + ((v4 + v5) + (v6 + v7));
            }
            for (; jj + 4 <= m; jj += 4) {
                int4 ia = *(const int4*)&ibuf[wv][jj];
                float v0 = hl[(size_t)ia.x * 64];
                float v1 = hl[(size_t)ia.y * 64];
                float v2 = hl[(size_t)ia.z * 64];
                float v3 = hl[(size_t)ia.w * 64];
                acc += (v0 + v1) + (v2 + v3);
            }
            for (; jj < m; ++jj) acc += hl[(size_t)ibuf[wv][jj] * 64];
        }
        xbuf[wv][lane] = acc;
        float outv = breg;
#pragma unroll
        for (int k4 = 0; k4 < 16; ++k4) {
            float4 xv = *(const float4*)&xbuf[wv][k4 * 4];
            outv = fmaf(xv.x, wcol[k4 * 4 + 0], outv);
            outv = fmaf(xv.y, wcol[k4 * 4 + 1], outv);
            outv = fmaf(xv.z, wcol[k4 * 4 + 2], outv);
            outv = fmaf(xv.w, wcol[k4 * 4 + 3], outv);
        }
        float h2v = fmaxf(outv, 0.f);
        float qv = h2v * whi;
        float rv = h2v * wlo;
#pragma unroll
        for (int off = 32; off >= 1; off >>= 1) {
            qv += __shfl_xor(qv, off, 64);
            rv += __shfl_xor(rv, off, 64);
        }
        if (lane == 0) {
            q[i] = qv;
            r[i] = rv;
        }
    }
}

// ============ pooling head ============

__global__ __launch_bounds__(256) void reduce_m2(const float* __restrict__ r,
                                                 float* __restrict__ m2, int N, int bpg) {
    int b = blockIdx.x / bpg, sub = blockIdx.x % bpg;
    const float* rb = r + (size_t)b * N;
    float a = 0.f;
    for (int n = sub * 256 + threadIdx.x; n < N; n += bpg * 256) a += rb[n];
    __shared__ float red[256];
    red[threadIdx.x] = a;
    __syncthreads();
    for (int off = 128; off >= 1; off >>= 1) {
        if (threadIdx.x < off) red[threadIdx.x] += red[threadIdx.x + off];
        __syncthreads();
    }
    if (threadIdx.x == 0) unsafeAtomicAdd(&m2[b], red[0]);
}

__global__ __launch_bounds__(256) void pathway_score_wave(const float* __restrict__ q,
                                                          const int* __restrict__ pathway,
                                                          const float* __restrict__ m2,
                                                          const float* __restrict__ blin,
                                                          float* __restrict__ s,
                                                          int N, int P, int L, float invN,
                                                          int B) {
    int wid = (int)((blockIdx.x * blockDim.x + threadIdx.x) >> 6);
    int lane = threadIdx.x & 63;
    if (wid >= B * P) return;
    int b = wid / P, p = wid % P;
    const int* pw = pathway + (size_t)p * L;
    const float* qb = q + (size_t)b * N;
    float sum = 0.f;
    for (int l = lane; l < L; l += 64) sum += qb[pw[l]];
#pragma unroll
    for (int off = 32; off >= 1; off >>= 1) sum += __shfl_xor(sum, off, 64);
    if (lane == 0) s[wid] = tanhf(sum + m2[b] * invN + blin[0]);
}

__global__ __launch_bounds__(64) void out_softmax_wave(const float* __restrict__ s,
                                                       const float* __restrict__ Wout,
                                                       const float* __restrict__ bout,
                                                       float* __restrict__ out, int P) {
    int b = blockIdx.x;
    int lane = threadIdx.x;
    const float* sb = s + (size_t)b * P;
    float a0 = 0.f, a1 = 0.f;
    for (int p = lane; p < P; p += 64) {
        float sv = sb[p];
        a0 = fmaf(sv, Wout[p * 2 + 0], a0);
        a1 = fmaf(sv, Wout[p * 2 + 1], a1);
    }
#pragma unroll
    for (int off = 32; off >= 1; off >>= 1) {
        a0 += __shfl_xor(a0, off, 64);
        a1 += __shfl_xor(a1, off, 64);
    }
    if (lane == 0) {
        float l0 = a0 + bout[0], l1 = a1 + bout[1];
        float m = fmaxf(l0, l1);
        float e0 = expf(l0 - m), e1 = expf(l1 - m);
        float inv = 1.f / (e0 + e1);
        out[b * 2 + 0] = e0 * inv;
        out[b * 2 + 1] = e1 * inv;
    }
}

extern "C" void kernel_launch(void* const* d_in, const int* in_sizes, int n_in,
                              void* d_out, int out_size, void* d_ws, size_t ws_size,
                              hipStream_t stream) {
    const float* h       = (const float*)d_in[0];
    const int*   src     = (const int*)d_in[1];
    const int*   dst     = (const int*)d_in[2];
    const int*   pathway = (const int*)d_in[3];
    const float* W1      = (const float*)d_in[5];
    const float* b1      = (const float*)d_in[6];
    const float* W2      = (const float*)d_in[7];
    const float* b2      = (const float*)d_in[8];
    const float* wlin    = (const float*)d_in[9];
    const float* blin    = (const float*)d_in[10];
    const float* Wout    = (const float*)d_in[11];
    const float* bout    = (const float*)d_in[12];
    float*       out     = (float*)d_out;

    const int BN = in_sizes[0] / 16;
    const int E  = in_sizes[1];
    const int P  = in_sizes[11] / 2;
    const int L  = in_sizes[3] / P;
    const int B  = out_size / 2;
    const int N  = BN / B;
    const int nb = (BN + 1023) / 1024;

    char* ws = (char*)d_ws;
    size_t o = 0;
    float* h1     = (float*)(ws + o); o += align256((size_t)BN * 64 * 4);
    float* qbuf   = (float*)(ws + o); o += align256((size_t)BN * 4);
    float* rbuf   = (float*)(ws + o); o += align256((size_t)BN * 4);
    float* m2     = (float*)(ws + o); o += align256((size_t)B * 4);
    float* sbuf   = (float*)(ws + o); o += align256((size_t)B * P * 4);
    int*   counts = (int*)(ws + o);   o += align256((size_t)BN * 4);
    int*   offs   = (int*)(ws + o);   o += align256((size_t)BN * 4);
    int*   cursor = (int*)(ws + o);   o += align256((size_t)BN * 4);
    int*   esrc   = (int*)(ws + o);   o += align256((size_t)E * 4);
    int2*  bins   = (int2*)(ws + o);  o += align256((size_t)E * 8);
    int*   btot   = (int*)(ws + o);   o += align256(64);
    int*   bcur   = (int*)(ws + o);   o += align256(64);
    int*   bsum   = (int*)(ws + o);   o += align256((size_t)nb * 4);
    int*   bpre   = (int*)(ws + o);   o += align256((size_t)nb * 4);
    (void)ws_size; (void)n_in;

    // ---- CSR build: bucket hist -> bin pairs -> sharded count -> scan -> sharded fill ----
    hipMemsetAsync(counts, 0, (size_t)BN * 4, stream);
    hipMemsetAsync(btot, 0, 64, stream);
    hipMemsetAsync(bcur, 0, 64, stream);
    hipMemsetAsync(m2, 0, (size_t)B * 4, stream);
    bucket_hist<<<1024, 256, 0, stream>>>(dst, btot, E, BN);
    bin_edges<<<(E + 1023) / 1024, 256, 0, stream>>>(src, dst, btot, bcur, bins, E, BN);
    count_binned<<<2048, 256, 0, stream>>>(bins, btot, counts, E);
    block_reduce<<<nb, 256, 0, stream>>>(counts, bsum, BN);
    scan_small<<<1, 1024, 0, stream>>>(bsum, bpre, nb);
    block_scan<<<nb, 256, 0, stream>>>(counts, bpre, offs, BN);
    hipMemcpyAsync(cursor, offs, (size_t)BN * 4, hipMemcpyDeviceToDevice, stream);
    fill_binned<<<2048, 256, 0, stream>>>(bins, btot, cursor, esrc, E);

    // ---- fused layer 1 (gather16 + lin1 + relu) ----
    gin1_fused<<<2048, 256, 0, stream>>>(h, offs, counts, esrc, W1, b1, h1, BN);

    // ---- fused layer 2 + projection (h2 never materialized) ----
    gather64_lin2_qr<<<2048, 256, 0, stream>>>(h1, offs, counts, esrc, W2, b2, wlin,
                                               qbuf, rbuf, BN);

    // ---- pooling head ----
    reduce_m2<<<B * 8, 256, 0, stream>>>(rbuf, m2, N, 8);
    pathway_score_wave<<<(B * P + 3) / 4, 256, 0, stream>>>(qbuf, pathway, m2, blin, sbuf,
                                                            N, P, L, 1.0f / (float)N, B);
    out_softmax_wave<<<B, 64, 0, stream>>>(sbuf, Wout, bout, out, P);
}

// Round 9
// 421.433 us; speedup vs baseline: 1.1285x; 1.1285x over previous
//
#include <hip/hip_runtime.h>
#include <hip/hip_bf16.h>
#include <math.h>

static inline size_t align256(size_t x) { return (x + 255) & ~size_t(255); }

// ============ CSR construction (dst-range sharded: shard s <-> XCD s) ============

// Each shard's blocks scan ALL edges, count only dst in [lo,hi).
// Counters for shard s live in an XCD-local L2 region -> no cross-XCD atomic ping-pong.
__global__ __launch_bounds__(256) void csr_count_shard(const int* __restrict__ dst,
                                                       int* __restrict__ counts, int E, int BN) {
    int s  = blockIdx.x & 7;
    int bs = blockIdx.x >> 3;
    int nb = gridDim.x >> 3;
    int lo = (int)(((long long)BN * s) >> 3);
    int hi = (int)(((long long)BN * (s + 1)) >> 3);
    for (int e = bs * 256 + threadIdx.x; e < E; e += nb * 256) {
        int d = dst[e];
        if (d >= lo && d < hi) atomicAdd(&counts[d], 1);
    }
}

__global__ __launch_bounds__(256) void block_reduce(const int* __restrict__ counts,
                                                    int* __restrict__ bsum, int BN) {
    __shared__ int red[256];
    int base = blockIdx.x * 1024;
    int s = 0;
    for (int k = threadIdx.x; k < 1024; k += 256) {
        int idx = base + k;
        s += (idx < BN) ? counts[idx] : 0;
    }
    red[threadIdx.x] = s;
    __syncthreads();
    for (int off = 128; off >= 1; off >>= 1) {
        if (threadIdx.x < off) red[threadIdx.x] += red[threadIdx.x + off];
        __syncthreads();
    }
    if (threadIdx.x == 0) bsum[blockIdx.x] = red[0];
}

__global__ __launch_bounds__(1024) void scan_small(const int* __restrict__ bsum,
                                                   int* __restrict__ bpre, int nb) {
    __shared__ int buf[1024];
    int tid = threadIdx.x;
    buf[tid] = (tid < nb) ? bsum[tid] : 0;
    __syncthreads();
    for (int off = 1; off < 1024; off <<= 1) {
        int v = (tid >= off) ? buf[tid - off] : 0;
        __syncthreads();
        buf[tid] += v;
        __syncthreads();
    }
    if (tid < nb) bpre[tid] = (tid == 0) ? 0 : buf[tid - 1];
}

__global__ __launch_bounds__(256) void block_scan(const int* __restrict__ counts,
                                                  const int* __restrict__ bpre,
                                                  int* __restrict__ offs, int BN) {
    __shared__ int tsum[256];
    int base = blockIdx.x * 1024;
    int tbase = base + threadIdx.x * 4;
    int c0 = 0, c1 = 0, c2 = 0, c3 = 0;
    if (tbase + 0 < BN) c0 = counts[tbase + 0];
    if (tbase + 1 < BN) c1 = counts[tbase + 1];
    if (tbase + 2 < BN) c2 = counts[tbase + 2];
    if (tbase + 3 < BN) c3 = counts[tbase + 3];
    int local = c0 + c1 + c2 + c3;
    tsum[threadIdx.x] = local;
    __syncthreads();
    for (int off = 1; off < 256; off <<= 1) {
        int v = (threadIdx.x >= off) ? tsum[threadIdx.x - off] : 0;
        __syncthreads();
        tsum[threadIdx.x] += v;
        __syncthreads();
    }
    int prefix = bpre[blockIdx.x] + tsum[threadIdx.x] - local;  // exclusive
    if (tbase + 0 < BN) offs[tbase + 0] = prefix;
    prefix += c0;
    if (tbase + 1 < BN) offs[tbase + 1] = prefix;
    prefix += c1;
    if (tbase + 2 < BN) offs[tbase + 2] = prefix;
    prefix += c2;
    if (tbase + 3 < BN) offs[tbase + 3] = prefix;
}

// Sharded fill with XCD-local cursor atomics (cursor/esrc region owned by one XCD).
__global__ __launch_bounds__(256) void csr_fill_shard(const int* __restrict__ src,
                                                      const int* __restrict__ dst,
                                                      int* __restrict__ cursor,
                                                      int* __restrict__ esrc, int E, int BN) {
    int s  = blockIdx.x & 7;
    int bs = blockIdx.x >> 3;
    int nb = gridDim.x >> 3;
    int lo = (int)(((long long)BN * s) >> 3);
    int hi = (int)(((long long)BN * (s + 1)) >> 3);
    for (int e = bs * 256 + threadIdx.x; e < E; e += nb * 256) {
        int d = dst[e];
        if (d >= lo && d < hi) esrc[atomicAdd(&cursor[d], 1)] = src[e];
    }
}

// ============ fused layer 1: gather16 + lin1 + relu -> bf16 h1 ============
// wave per node. lane = 16*group + feat; 4 neighbor rows processed in parallel.
__global__ __launch_bounds__(256) void gin1_fused(const float* __restrict__ h,
                                                  const int* __restrict__ offs,
                                                  const int* __restrict__ cnts,
                                                  const int* __restrict__ esrc,
                                                  const float* __restrict__ W1,
                                                  const float* __restrict__ b1,
                                                  __hip_bfloat16* __restrict__ h1, int BN) {
    __shared__ float xb[4][16];
    __shared__ int   ibuf[4][64];
    int tid = threadIdx.x;
    int lane = tid & 63, wv = tid >> 6;
    int fg = lane >> 4, ft = lane & 15;
    int gw = (int)((blockIdx.x * blockDim.x + tid) >> 6);
    int nw = (int)((gridDim.x * blockDim.x) >> 6);
    float wcol[16];
#pragma unroll
    for (int k = 0; k < 16; ++k) wcol[k] = W1[k * 64 + lane];
    float breg = b1[lane];
    for (int i = gw; i < BN; i += nw) {
        float acc = (fg == 0) ? h[(size_t)i * 16 + ft] : 0.f;
        int start = offs[i], deg = cnts[i];
        for (int j0 = 0; j0 < deg; j0 += 64) {
            int m = min(64, deg - j0);
            if (lane < m) ibuf[wv][lane] = esrc[start + j0 + lane];
            int jj = fg;
            for (; jj + 4 < m; jj += 8) {
                int s0 = ibuf[wv][jj];
                int s1 = ibuf[wv][jj + 4];
                acc += h[(size_t)s0 * 16 + ft] + h[(size_t)s1 * 16 + ft];
            }
            if (jj < m) acc += h[(size_t)ibuf[wv][jj] * 16 + ft];
        }
        acc += __shfl_xor(acc, 16, 64);
        acc += __shfl_xor(acc, 32, 64);
        if (lane < 16) xb[wv][lane] = acc;
        float o = breg;
#pragma unroll
        for (int k4 = 0; k4 < 4; ++k4) {
            float4 xv = *(const float4*)&xb[wv][k4 * 4];
            o = fmaf(xv.x, wcol[k4 * 4 + 0], o);
            o = fmaf(xv.y, wcol[k4 * 4 + 1], o);
            o = fmaf(xv.z, wcol[k4 * 4 + 2], o);
            o = fmaf(xv.w, wcol[k4 * 4 + 3], o);
        }
        h1[(size_t)i * 64 + lane] = __float2bfloat16(fmaxf(o, 0.f));
    }
}

// ============ fused layer 2: gather(bf16) + lin2 + relu + project to (q, r) ============
__global__ __launch_bounds__(256, 4) void gather64_lin2_qr(const __hip_bfloat16* __restrict__ h1,
                                                           const int* __restrict__ offs,
                                                           const int* __restrict__ cnts,
                                                           const int* __restrict__ esrc,
                                                           const float* __restrict__ W2,
                                                           const float* __restrict__ b2,
                                                           const float* __restrict__ wlin,
                                                           float* __restrict__ q,
                                                           float* __restrict__ r, int BN) {
    __shared__ float xbuf[4][64];
    __shared__ int   ibuf[4][64];
    int tid = threadIdx.x;
    int lane = tid & 63, wv = tid >> 6;
    int gw = (int)((blockIdx.x * blockDim.x + tid) >> 6);
    int nw = (int)((gridDim.x * blockDim.x) >> 6);
    float wcol[64];
#pragma unroll
    for (int k = 0; k < 64; ++k) wcol[k] = W2[k * 64 + lane];
    float breg = b2[lane];
    float wlo = wlin[lane];
    float whi = wlin[64 + lane];
    const __hip_bfloat16* hl = h1 + lane;
    for (int i = gw; i < BN; i += nw) {
        float acc = __bfloat162float(hl[(size_t)i * 64]);
        int start = offs[i], deg = cnts[i];
        for (int j0 = 0; j0 < deg; j0 += 64) {
            int m = min(64, deg - j0);
            if (lane < m) ibuf[wv][lane] = esrc[start + j0 + lane];
            int jj = 0;
            for (; jj + 8 <= m; jj += 8) {
                int4 ia = *(const int4*)&ibuf[wv][jj];
                int4 ib = *(const int4*)&ibuf[wv][jj + 4];
                float v0 = __bfloat162float(hl[(size_t)ia.x * 64]);
                float v1 = __bfloat162float(hl[(size_t)ia.y * 64]);
                float v2 = __bfloat162float(hl[(size_t)ia.z * 64]);
                float v3 = __bfloat162float(hl[(size_t)ia.w * 64]);
                float v4 = __bfloat162float(hl[(size_t)ib.x * 64]);
                float v5 = __bfloat162float(hl[(size_t)ib.y * 64]);
                float v6 = __bfloat162float(hl[(size_t)ib.z * 64]);
                float v7 = __bfloat162float(hl[(size_t)ib.w * 64]);
                acc += ((v0 + v1) + (v2 + v3)) + ((v4 + v5) + (v6 + v7));
            }
            for (; jj + 4 <= m; jj += 4) {
                int4 ia = *(const int4*)&ibuf[wv][jj];
                float v0 = __bfloat162float(hl[(size_t)ia.x * 64]);
                float v1 = __bfloat162float(hl[(size_t)ia.y * 64]);
                float v2 = __bfloat162float(hl[(size_t)ia.z * 64]);
                float v3 = __bfloat162float(hl[(size_t)ia.w * 64]);
                acc += (v0 + v1) + (v2 + v3);
            }
            for (; jj < m; ++jj) acc += __bfloat162float(hl[(size_t)ibuf[wv][jj] * 64]);
        }
        xbuf[wv][lane] = acc;
        float outv = breg;
#pragma unroll
        for (int k4 = 0; k4 < 16; ++k4) {
            float4 xv = *(const float4*)&xbuf[wv][k4 * 4];
            outv = fmaf(xv.x, wcol[k4 * 4 + 0], outv);
            outv = fmaf(xv.y, wcol[k4 * 4 + 1], outv);
            outv = fmaf(xv.z, wcol[k4 * 4 + 2], outv);
            outv = fmaf(xv.w, wcol[k4 * 4 + 3], outv);
        }
        float h2v = fmaxf(outv, 0.f);
        float qv = h2v * whi;
        float rv = h2v * wlo;
#pragma unroll
        for (int off = 32; off >= 1; off >>= 1) {
            qv += __shfl_xor(qv, off, 64);
            rv += __shfl_xor(rv, off, 64);
        }
        if (lane == 0) {
            q[i] = qv;
            r[i] = rv;
        }
    }
}

// ============ pooling head ============

__global__ __launch_bounds__(256) void reduce_m2(const float* __restrict__ r,
                                                 float* __restrict__ m2, int N, int bpg) {
    int b = blockIdx.x / bpg, sub = blockIdx.x % bpg;
    const float* rb = r + (size_t)b * N;
    float a = 0.f;
    for (int n = sub * 256 + threadIdx.x; n < N; n += bpg * 256) a += rb[n];
    __shared__ float red[256];
    red[threadIdx.x] = a;
    __syncthreads();
    for (int off = 128; off >= 1; off >>= 1) {
        if (threadIdx.x < off) red[threadIdx.x] += red[threadIdx.x + off];
        __syncthreads();
    }
    if (threadIdx.x == 0) unsafeAtomicAdd(&m2[b], red[0]);
}

__global__ __launch_bounds__(256) void pathway_score_wave(const float* __restrict__ q,
                                                          const int* __restrict__ pathway,
                                                          const float* __restrict__ m2,
                                                          const float* __restrict__ blin,
                                                          float* __restrict__ s,
                                                          int N, int P, int L, float invN,
                                                          int B) {
    int wid = (int)((blockIdx.x * blockDim.x + threadIdx.x) >> 6);
    int lane = threadIdx.x & 63;
    if (wid >= B * P) return;
    int b = wid / P, p = wid % P;
    const int* pw = pathway + (size_t)p * L;
    const float* qb = q + (size_t)b * N;
    float sum = 0.f;
    for (int l = lane; l < L; l += 64) sum += qb[pw[l]];
#pragma unroll
    for (int off = 32; off >= 1; off >>= 1) sum += __shfl_xor(sum, off, 64);
    if (lane == 0) s[wid] = tanhf(sum + m2[b] * invN + blin[0]);
}

__global__ __launch_bounds__(64) void out_softmax_wave(const float* __restrict__ s,
                                                       const float* __restrict__ Wout,
                                                       const float* __restrict__ bout,
                                                       float* __restrict__ out, int P) {
    int b = blockIdx.x;
    int lane = threadIdx.x;
    const float* sb = s + (size_t)b * P;
    float a0 = 0.f, a1 = 0.f;
    for (int p = lane; p < P; p += 64) {
        float sv = sb[p];
        a0 = fmaf(sv, Wout[p * 2 + 0], a0);
        a1 = fmaf(sv, Wout[p * 2 + 1], a1);
    }
#pragma unroll
    for (int off = 32; off >= 1; off >>= 1) {
        a0 += __shfl_xor(a0, off, 64);
        a1 += __shfl_xor(a1, off, 64);
    }
    if (lane == 0) {
        float l0 = a0 + bout[0], l1 = a1 + bout[1];
        float m = fmaxf(l0, l1);
        float e0 = expf(l0 - m), e1 = expf(l1 - m);
        float inv = 1.f / (e0 + e1);
        out[b * 2 + 0] = e0 * inv;
        out[b * 2 + 1] = e1 * inv;
    }
}

extern "C" void kernel_launch(void* const* d_in, const int* in_sizes, int n_in,
                              void* d_out, int out_size, void* d_ws, size_t ws_size,
                              hipStream_t stream) {
    const float* h       = (const float*)d_in[0];
    const int*   src     = (const int*)d_in[1];
    const int*   dst     = (const int*)d_in[2];
    const int*   pathway = (const int*)d_in[3];
    const float* W1      = (const float*)d_in[5];
    const float* b1      = (const float*)d_in[6];
    const float* W2      = (const float*)d_in[7];
    const float* b2      = (const float*)d_in[8];
    const float* wlin    = (const float*)d_in[9];
    const float* blin    = (const float*)d_in[10];
    const float* Wout    = (const float*)d_in[11];
    const float* bout    = (const float*)d_in[12];
    float*       out     = (float*)d_out;

    const int BN = in_sizes[0] / 16;
    const int E  = in_sizes[1];
    const int P  = in_sizes[11] / 2;
    const int L  = in_sizes[3] / P;
    const int B  = out_size / 2;
    const int N  = BN / B;
    const int nb = (BN + 1023) / 1024;

    char* ws = (char*)d_ws;
    size_t o = 0;
    __hip_bfloat16* h1 = (__hip_bfloat16*)(ws + o); o += align256((size_t)BN * 64 * 2);
    float* qbuf   = (float*)(ws + o); o += align256((size_t)BN * 4);
    float* rbuf   = (float*)(ws + o); o += align256((size_t)BN * 4);
    float* m2     = (float*)(ws + o); o += align256((size_t)B * 4);
    float* sbuf   = (float*)(ws + o); o += align256((size_t)B * P * 4);
    int*   counts = (int*)(ws + o);   o += align256((size_t)BN * 4);
    int*   offs   = (int*)(ws + o);   o += align256((size_t)BN * 4);
    int*   cursor = (int*)(ws + o);   o += align256((size_t)BN * 4);
    int*   esrc   = (int*)(ws + o);   o += align256((size_t)E * 4);
    int*   bsum   = (int*)(ws + o);   o += align256((size_t)nb * 4);
    int*   bpre   = (int*)(ws + o);   o += align256((size_t)nb * 4);
    (void)ws_size; (void)n_in;

    // ---- build CSR (dst -> list of src), XCD-sharded atomics & stores ----
    hipMemsetAsync(counts, 0, (size_t)BN * 4, stream);
    hipMemsetAsync(m2, 0, (size_t)B * 4, stream);
    csr_count_shard<<<2048, 256, 0, stream>>>(dst, counts, E, BN);
    block_reduce<<<nb, 256, 0, stream>>>(counts, bsum, BN);
    scan_small<<<1, 1024, 0, stream>>>(bsum, bpre, nb);
    block_scan<<<nb, 256, 0, stream>>>(counts, bpre, offs, BN);
    hipMemcpyAsync(cursor, offs, (size_t)BN * 4, hipMemcpyDeviceToDevice, stream);
    csr_fill_shard<<<2048, 256, 0, stream>>>(src, dst, cursor, esrc, E, BN);

    // ---- fused layer 1 (gather16 + lin1 + relu), bf16 output ----
    gin1_fused<<<2048, 256, 0, stream>>>(h, offs, counts, esrc, W1, b1, h1, BN);

    // ---- fused layer 2 + projection (h2 never materialized) ----
    gather64_lin2_qr<<<2048, 256, 0, stream>>>(h1, offs, counts, esrc, W2, b2, wlin,
                                               qbuf, rbuf, BN);

    // ---- pooling head ----
    reduce_m2<<<B * 8, 256, 0, stream>>>(rbuf, m2, N, 8);
    pathway_score_wave<<<(B * P + 3) / 4, 256, 0, stream>>>(qbuf, pathway, m2, blin, sbuf,
                                                            N, P, L, 1.0f / (float)N, B);
    out_softmax_wave<<<B, 64, 0, stream>>>(sbuf, Wout, bout, out, P);
}